// Round 2
// baseline (1388.725 us; speedup 1.0000x reference)
//
#include <hip/hip_runtime.h>
#include <hip/hip_bf16.h>
#include <type_traits>

typedef __bf16 bf16_t;
typedef __attribute__((ext_vector_type(8))) __bf16 bf16x8;
typedef __attribute__((ext_vector_type(4))) float f32x4;

#define B_ 2
#define S_ 2048
#define D_ 1024
#define H_ 16
#define DK_ 64

// split a run of 8 fp32 into bf16 hi + bf16 lo (residual) parts
__device__ inline void split8(const float* __restrict__ p, bf16x8& h, bf16x8& l) {
    float4 x0 = *(const float4*)p;
    float4 x1 = *(const float4*)(p + 4);
    float xs[8] = {x0.x, x0.y, x0.z, x0.w, x1.x, x1.y, x1.z, x1.w};
#pragma unroll
    for (int i = 0; i < 8; ++i) {
        bf16_t hh = (bf16_t)xs[i];
        h[i] = hh;
        l[i] = (bf16_t)(xs[i] - (float)hh);
    }
}
__device__ inline void hi8(const float* __restrict__ p, bf16x8& h) {
    float4 x0 = *(const float4*)p;
    float4 x1 = *(const float4*)(p + 4);
    float xs[8] = {x0.x, x0.y, x0.z, x0.w, x1.x, x1.y, x1.z, x1.w};
#pragma unroll
    for (int i = 0; i < 8; ++i) h[i] = (bf16_t)xs[i];
}

// ---------------------------------------------------------------------------
// GEMM: Y[M,N] = A[M,K] @ W[N,K]^T + bias[N].
// A: fp32 or bf16 (template). W,bias fp32. Y: fp32 or bf16 (template).
// SPLIT: hi/lo-split bf16 MFMA (3 products) for ~fp32 accuracy.
// Block tile 64x64, 4 waves 2x2, each wave 2x2 mfma_f32_16x16x32_bf16.
// ---------------------------------------------------------------------------
template <typename AT, typename OT, bool SPLIT>
__global__ __launch_bounds__(256) void gemm_bt(
    const AT* __restrict__ A,
    const float* __restrict__ W,
    const float* __restrict__ bias,
    OT* __restrict__ Y,
    int M, int N, int K)
{
    const int NB = N >> 6;
    const int bm = blockIdx.x / NB;
    const int bn = blockIdx.x % NB;
    const int tid  = threadIdx.x;
    const int wave = tid >> 6;
    const int lane = tid & 63;
    const int l16  = lane & 15;
    const int quad = lane >> 4;
    const int wm = wave >> 1, wn = wave & 1;

    __shared__ bf16_t Ah[64][40];
    __shared__ bf16_t Wh[64][40];
    __shared__ bf16_t Al[SPLIT ? 64 : 1][40];
    __shared__ bf16_t Wl[SPLIT ? 64 : 1][40];

    const int srow = tid >> 2;        // 0..63
    const int scol = (tid & 3) * 8;   // 0,8,16,24

    f32x4 acc[2][2];
#pragma unroll
    for (int i = 0; i < 2; ++i)
#pragma unroll
        for (int j = 0; j < 2; ++j) acc[i][j] = (f32x4){0.f, 0.f, 0.f, 0.f};

    const AT*    Arow = A + (size_t)(bm * 64 + srow) * K + scol;
    const float* Wrow = W + (size_t)(bn * 64 + srow) * K + scol;

    for (int k0 = 0; k0 < K; k0 += 32) {
        if constexpr (std::is_same_v<AT, float>) {
            bf16x8 ah, al;
            if constexpr (SPLIT) {
                split8(Arow + k0, ah, al);
                *(bf16x8*)(&Al[srow][scol]) = al;
            } else {
                hi8(Arow + k0, ah);
            }
            *(bf16x8*)(&Ah[srow][scol]) = ah;
        } else {
            *(bf16x8*)(&Ah[srow][scol]) = *(const bf16x8*)(Arow + k0);
        }
        {
            bf16x8 wh, wl;
            if constexpr (SPLIT) {
                split8(Wrow + k0, wh, wl);
                *(bf16x8*)(&Wl[srow][scol]) = wl;
            } else {
                hi8(Wrow + k0, wh);
            }
            *(bf16x8*)(&Wh[srow][scol]) = wh;
        }
        __syncthreads();

        bf16x8 afh[2], bfh[2], afl[2], bfl[2];
#pragma unroll
        for (int mi = 0; mi < 2; ++mi) {
            afh[mi] = *(const bf16x8*)(&Ah[wm * 32 + mi * 16 + l16][quad * 8]);
            if constexpr (SPLIT)
                afl[mi] = *(const bf16x8*)(&Al[wm * 32 + mi * 16 + l16][quad * 8]);
        }
#pragma unroll
        for (int ni = 0; ni < 2; ++ni) {
            bfh[ni] = *(const bf16x8*)(&Wh[wn * 32 + ni * 16 + l16][quad * 8]);
            if constexpr (SPLIT)
                bfl[ni] = *(const bf16x8*)(&Wl[wn * 32 + ni * 16 + l16][quad * 8]);
        }

#pragma unroll
        for (int mi = 0; mi < 2; ++mi)
#pragma unroll
            for (int ni = 0; ni < 2; ++ni) {
                acc[mi][ni] = __builtin_amdgcn_mfma_f32_16x16x32_bf16(
                    afh[mi], bfh[ni], acc[mi][ni], 0, 0, 0);
                if constexpr (SPLIT) {
                    acc[mi][ni] = __builtin_amdgcn_mfma_f32_16x16x32_bf16(
                        afl[mi], bfh[ni], acc[mi][ni], 0, 0, 0);
                    acc[mi][ni] = __builtin_amdgcn_mfma_f32_16x16x32_bf16(
                        afh[mi], bfl[ni], acc[mi][ni], 0, 0, 0);
                }
            }
        __syncthreads();
    }

#pragma unroll
    for (int ni = 0; ni < 2; ++ni) {
        const int col = bn * 64 + wn * 32 + ni * 16 + l16;
        const float bv = bias[col];
#pragma unroll
        for (int mi = 0; mi < 2; ++mi) {
#pragma unroll
            for (int r = 0; r < 4; ++r) {
                const int row = bm * 64 + wm * 32 + mi * 16 + quad * 4 + r;
                Y[(size_t)row * N + col] = (OT)(acc[mi][ni][r] + bv);
            }
        }
    }
}

// ---------------------------------------------------------------------------
// Attention. q,k in fp32 (split hi/lo on the fly for ~fp32-accurate scores),
// v in bf16. Per block = (b, h, 64 q-rows); wave w owns 16 q-rows.
// Pass 1: l[row] = sum_j exp(score/8) (no max-subtract; |score/8| < ~6).
// Pass 2: recompute scores, w = exp * 2048/l; store fp32 weights from
// C-layout; bf16 w via LDS (C->A layout) for the PV MFMA.
// ---------------------------------------------------------------------------
__global__ __launch_bounds__(256) void attn_kernel(
    const float*  __restrict__ qp,   // [B,S,D] fp32
    const float*  __restrict__ kp,   // [B,S,D] fp32
    const bf16_t* __restrict__ vp,   // [B,S,D] bf16
    const int*    __restrict__ mask, // [B,S,S] int 0/1, 1 = masked
    float* __restrict__ wout,        // [B,H,S,S] fp32
    bf16_t* __restrict__ ctx)        // [B,S,D] bf16
{
    const int bid = blockIdx.x;       // B*H*(S/64) = 1024
    const int qt = bid & 31;
    const int h  = (bid >> 5) & 15;
    const int b  = bid >> 9;
    const int tid  = threadIdx.x;
    const int wave = tid >> 6;
    const int lane = tid & 63;
    const int l16  = lane & 15;
    const int quad = lane >> 4;

    const int q0 = qt * 64 + wave * 16;

    __shared__ bf16_t vT[64][40];        // [dk][j]
    __shared__ bf16_t wl[4][16][40];     // per-wave w tile [q][j]

    // q fragments (A operand), hi/lo, held for both passes
    const float* qbase = qp + ((size_t)(b * S_ + q0 + l16)) * D_ + h * DK_ + quad * 8;
    bf16x8 qh0, ql0, qh1, ql1;
    split8(qbase, qh0, ql0);
    split8(qbase + 32, qh1, ql1);

    const float scale = 0.125f;  // 1/sqrt(64)
    const size_t mbase = (size_t)b * S_ * S_;

    float lsum[4] = {0.f, 0.f, 0.f, 0.f};

    // ---- Pass 1: softmax denominators ----
    for (int j0 = 0; j0 < S_; j0 += 16) {
        const float* kb = kp + ((size_t)(b * S_ + j0 + l16)) * D_ + h * DK_ + quad * 8;
        bf16x8 kh0, kl0, kh1, kl1;
        split8(kb, kh0, kl0);
        split8(kb + 32, kh1, kl1);
        f32x4 c = (f32x4){0.f, 0.f, 0.f, 0.f};
        c = __builtin_amdgcn_mfma_f32_16x16x32_bf16(qh0, kh0, c, 0, 0, 0);
        c = __builtin_amdgcn_mfma_f32_16x16x32_bf16(qh1, kh1, c, 0, 0, 0);
        c = __builtin_amdgcn_mfma_f32_16x16x32_bf16(ql0, kh0, c, 0, 0, 0);
        c = __builtin_amdgcn_mfma_f32_16x16x32_bf16(ql1, kh1, c, 0, 0, 0);
        c = __builtin_amdgcn_mfma_f32_16x16x32_bf16(qh0, kl0, c, 0, 0, 0);
        c = __builtin_amdgcn_mfma_f32_16x16x32_bf16(qh1, kl1, c, 0, 0, 0);
#pragma unroll
        for (int r = 0; r < 4; ++r) {
            const int q = q0 + quad * 4 + r;
            const int msk = mask[mbase + (size_t)q * S_ + j0 + l16];
            lsum[r] += msk ? 0.f : __expf(c[r] * scale);
        }
    }
#pragma unroll
    for (int r = 0; r < 4; ++r) {
        float v = lsum[r];
        v += __shfl_xor(v, 1);
        v += __shfl_xor(v, 2);
        v += __shfl_xor(v, 4);
        v += __shfl_xor(v, 8);
        lsum[r] = v;
    }
    float norm[4];
#pragma unroll
    for (int r = 0; r < 4; ++r) norm[r] = 2048.f / lsum[r];

    // ---- Pass 2: weights + PV ----
    f32x4 acc[4];
#pragma unroll
    for (int t = 0; t < 4; ++t) acc[t] = (f32x4){0.f, 0.f, 0.f, 0.f};

    const size_t wbase = ((size_t)(b * H_ + h)) * S_ * S_;

    for (int j0 = 0; j0 < S_; j0 += 32) {
        // stage V^T tile [dk][j] from bf16 vp
        {
            const int j   = tid >> 3;        // 0..31
            const int dk8 = (tid & 7) * 8;   // 0..56
            const bf16_t* vb = vp + ((size_t)(b * S_ + j0 + j)) * D_ + h * DK_ + dk8;
            const bf16x8 vv = *(const bf16x8*)vb;
#pragma unroll
            for (int i = 0; i < 8; ++i) vT[dk8 + i][j] = vv[i];
        }
#pragma unroll
        for (int sub = 0; sub < 2; ++sub) {
            const int jt = j0 + sub * 16;
            const float* kb = kp + ((size_t)(b * S_ + jt + l16)) * D_ + h * DK_ + quad * 8;
            bf16x8 kh0, kl0, kh1, kl1;
            split8(kb, kh0, kl0);
            split8(kb + 32, kh1, kl1);
            f32x4 c = (f32x4){0.f, 0.f, 0.f, 0.f};
            c = __builtin_amdgcn_mfma_f32_16x16x32_bf16(qh0, kh0, c, 0, 0, 0);
            c = __builtin_amdgcn_mfma_f32_16x16x32_bf16(qh1, kh1, c, 0, 0, 0);
            c = __builtin_amdgcn_mfma_f32_16x16x32_bf16(ql0, kh0, c, 0, 0, 0);
            c = __builtin_amdgcn_mfma_f32_16x16x32_bf16(ql1, kh1, c, 0, 0, 0);
            c = __builtin_amdgcn_mfma_f32_16x16x32_bf16(qh0, kl0, c, 0, 0, 0);
            c = __builtin_amdgcn_mfma_f32_16x16x32_bf16(qh1, kl1, c, 0, 0, 0);
#pragma unroll
            for (int r = 0; r < 4; ++r) {
                const int q = q0 + quad * 4 + r;
                const int msk = mask[mbase + (size_t)q * S_ + jt + l16];
                const float w = msk ? 0.f : __expf(c[r] * scale) * norm[r];
                wout[wbase + (size_t)q * S_ + jt + l16] = w;      // exact fp32
                wl[wave][quad * 4 + r][sub * 16 + l16] = (bf16_t)w;
            }
        }
        __syncthreads();
        const bf16x8 wa = *(const bf16x8*)(&wl[wave][l16][quad * 8]);
#pragma unroll
        for (int t = 0; t < 4; ++t) {
            const bf16x8 vf = *(const bf16x8*)(&vT[t * 16 + l16][quad * 8]);
            acc[t] = __builtin_amdgcn_mfma_f32_16x16x32_bf16(wa, vf, acc[t], 0, 0, 0);
        }
        __syncthreads();
    }

#pragma unroll
    for (int t = 0; t < 4; ++t) {
#pragma unroll
        for (int r = 0; r < 4; ++r) {
            const int q = q0 + quad * 4 + r;
            ctx[((size_t)(b * S_ + q)) * D_ + h * DK_ + t * 16 + l16] =
                (bf16_t)acc[t][r];
        }
    }
}

// ---------------------------------------------------------------------------
extern "C" void kernel_launch(void* const* d_in, const int* in_sizes, int n_in,
                              void* d_out, int out_size, void* d_ws, size_t ws_size,
                              hipStream_t stream) {
    const float* Q    = (const float*)d_in[0];
    const float* K    = (const float*)d_in[1];
    const float* V    = (const float*)d_in[2];
    const int*   mask = (const int*)d_in[3];
    const float* Wq   = (const float*)d_in[4];
    const float* bq   = (const float*)d_in[5];
    const float* Wk   = (const float*)d_in[6];
    const float* bk   = (const float*)d_in[7];
    const float* Wv   = (const float*)d_in[8];
    const float* bv   = (const float*)d_in[9];
    const float* Wo   = (const float*)d_in[10];
    const float* bo   = (const float*)d_in[11];

    const size_t BSD = (size_t)B_ * S_ * D_;  // 4,194,304
    float* out  = (float*)d_out;              // [B,S,D] fp32
    float* wout = out + BSD;                  // [B,H,S,S] fp32

    float*  qp  = (float*)d_ws;               // fp32 q (for hi/lo split)
    float*  kpf = qp + BSD;                   // fp32 k
    bf16_t* vp  = (bf16_t*)(kpf + BSD);       // bf16 v
    bf16_t* cx  = vp + BSD;                   // bf16 ctx

    const int M = B_ * S_;   // 4096
    const int N = D_;        // 1024
    const int Kd = D_;       // 1024
    const dim3 ggrid((M / 64) * (N / 64));    // 1024
    const dim3 gblk(256);

    gemm_bt<float, float, true><<<ggrid, gblk, 0, stream>>>(Q, Wq, bq, qp, M, N, Kd);
    gemm_bt<float, float, true><<<ggrid, gblk, 0, stream>>>(K, Wk, bk, kpf, M, N, Kd);
    gemm_bt<float, bf16_t, false><<<ggrid, gblk, 0, stream>>>(V, Wv, bv, vp, M, N, Kd);

    attn_kernel<<<dim3(B_ * H_ * (S_ / 64)), gblk, 0, stream>>>(
        qp, kpf, vp, mask, wout, cx);

    gemm_bt<bf16_t, float, false><<<ggrid, gblk, 0, stream>>>(cx, Wo, bo, out, M, N, Kd);
}